// Round 1
// baseline (206.287 us; speedup 1.0000x reference)
//
#include <hip/hip_runtime.h>
#include <cstdint>

#define BSZ   8192
#define NGT   8
#define ROW   90     // B*5 + C
#define CELLS 49     // 7*7
#define WAVES 4
#define BLOCK 256
#define GRID  512    // 512*4 = 2048 waves, 4 batches each

__global__ void zero_out_kernel(float* out) { out[0] = 0.0f; }

__launch_bounds__(BLOCK, 4)
__global__ void yolo_loss_kernel(const float* __restrict__ preds,
                                 const float* __restrict__ gtb,
                                 const int*   __restrict__ gtl,
                                 float* __restrict__ out)
{
    __shared__ int      s_gi[WAVES][NGT], s_gj[WAVES][NGT];
    __shared__ int      s_best[WAVES][NGT], s_label[WAVES][NGT];
    __shared__ float    s_iou[WAVES][NGT];
    __shared__ float    s_cv[WAVES][NGT][4];
    __shared__ float    s_pb[WAVES][NGT][5];
    __shared__ uint32_t s_bits[WAVES][NGT][3];
    __shared__ unsigned char s_fin[WAVES][NGT], s_rep[WAVES][NGT];
    __shared__ float    s_red[WAVES];

    const int tid  = threadIdx.x;
    const int w    = tid >> 6;
    const int lane = tid & 63;
    const int wave_id = blockIdx.x * WAVES + w;
    const int nwaves  = GRID * WAVES;

    float acc = 0.0f;

    const int iters = (BSZ + nwaves - 1) / nwaves;   // == 4
    for (int it = 0; it < iters; ++it) {
        const int  b      = wave_id + it * nwaves;
        const bool active = (b < BSZ);

        // ---- Phase A: per-GT box computation (lanes 0..7) ----
        if (active && lane < NGT) {
            const int k = lane;
            const float* gb = gtb + ((size_t)b * NGT + k) * 4;
            float x1 = gb[0], y1 = gb[1], x2 = gb[2], y2 = gb[3];
            float gcx = (x1 + x2) * 0.5f, gcy = (y1 + y2) * 0.5f;
            float gw = x2 - x1, gh = y2 - y1;
            int gi = (int)(gcx * 7.0f); gi = gi < 0 ? 0 : (gi > 6 ? 6 : gi);
            int gj = (int)(gcy * 7.0f); gj = gj < 0 ? 0 : (gj > 6 ? 6 : gj);
            const float* pc = preds + ((size_t)b * CELLS + gj * 7 + gi) * ROW;
            float p[10];
            #pragma unroll
            for (int i = 0; i < 10; ++i) p[i] = pc[i];
            float ious[2];
            #pragma unroll
            for (int bb = 0; bb < 2; ++bb) {
                float pcx = (p[bb*5+0] + (float)gi) / 7.0f;
                float pcy = (p[bb*5+1] + (float)gj) / 7.0f;
                float pw  = p[bb*5+2] * p[bb*5+2];
                float ph  = p[bb*5+3] * p[bb*5+3];
                float bx1 = pcx - pw * 0.5f, by1 = pcy - ph * 0.5f;
                float bx2 = pcx + pw * 0.5f, by2 = pcy + ph * 0.5f;
                float ix1 = fmaxf(bx1, x1), iy1 = fmaxf(by1, y1);
                float ix2 = fminf(bx2, x2), iy2 = fminf(by2, y2);
                float inter = fmaxf(ix2 - ix1, 0.0f) * fmaxf(iy2 - iy1, 0.0f);
                float a1 = fmaxf(bx2 - bx1, 0.0f) * fmaxf(by2 - by1, 0.0f);
                float a2 = fmaxf(x2 - x1, 0.0f) * fmaxf(y2 - y1, 0.0f);
                ious[bb] = inter / (a1 + a2 - inter + 1e-6f);
            }
            int best = (ious[1] > ious[0]) ? 1 : 0;   // argmax: first max wins
            s_gi[w][k] = gi; s_gj[w][k] = gj; s_best[w][k] = best;
            s_iou[w][k] = ious[best];
            s_cv[w][k][0] = gcx * 7.0f - (float)gi;
            s_cv[w][k][1] = gcy * 7.0f - (float)gj;
            s_cv[w][k][2] = sqrtf(gw);
            s_cv[w][k][3] = sqrtf(gh);
            #pragma unroll
            for (int f = 0; f < 5; ++f) s_pb[w][k][f] = p[best*5+f];
            s_label[w][k] = gtl[(size_t)b * NGT + k];
        }
        __syncthreads();

        // ---- Phase B: scan semantics — last writer per slot, unique cells ----
        if (active && lane < NGT) {
            const int k = lane;
            int cell = s_gj[w][k]*7 + s_gi[w][k];
            int slot = cell*2 + s_best[w][k];
            unsigned char fin = 1;     // is k the LAST writer of this slot?
            for (int k2 = k+1; k2 < NGT; ++k2) {
                int slot2 = (s_gj[w][k2]*7 + s_gi[w][k2])*2 + s_best[w][k2];
                if (slot2 == slot) fin = 0;
            }
            unsigned char rep = 1;     // is k the FIRST occurrence of this cell?
            for (int k2 = 0; k2 < k; ++k2)
                if (s_gj[w][k2]*7 + s_gi[w][k2] == cell) rep = 0;
            uint32_t b0 = 0, b1 = 0, b2 = 0;
            if (rep) {                 // union of labels landing in this cell
                for (int k2 = 0; k2 < NGT; ++k2) {
                    if (s_gj[w][k2]*7 + s_gi[w][k2] == cell) {
                        int l = s_label[w][k2];
                        if (l < 32)      b0 |= 1u << l;
                        else if (l < 64) b1 |= 1u << (l - 32);
                        else             b2 |= 1u << (l - 64);
                    }
                }
            }
            s_fin[w][k] = fin; s_rep[w][k] = rep;
            s_bits[w][k][0] = b0; s_bits[w][k][1] = b1; s_bits[w][k][2] = b2;
        }
        __syncthreads();

        // ---- Phase C: accumulate loss pieces ----
        if (active) {
            // slot corrections: coord + obj + (−noobj baseline) for final slots
            if (lane < NGT && s_fin[w][lane]) {
                const int k = lane;
                float c = 0.0f;
                #pragma unroll
                for (int f = 0; f < 4; ++f) {
                    float d = s_pb[w][k][f] - s_cv[w][k][f];
                    c += d * d;
                }
                acc += 5.0f * c;
                float p4 = s_pb[w][k][4];
                float d  = p4 - s_iou[w][k];
                acc += d * d - 0.5f * p4 * p4;
            }
            // class corrections: 8 lanes per GT-index group, 10 classes each
            {
                int g = lane >> 3, sub = lane & 7;
                if (s_rep[w][g]) {
                    int cell = s_gj[w][g]*7 + s_gi[w][g];
                    const float* pcl = preds + ((size_t)b * CELLS + cell) * ROW + 10;
                    uint32_t b0 = s_bits[w][g][0], b1 = s_bits[w][g][1], b2 = s_bits[w][g][2];
                    #pragma unroll
                    for (int t = 0; t < 10; ++t) {
                        int c = sub + (t << 3);          // covers 0..79 exactly once
                        float p = pcl[c];
                        uint32_t bit = (c < 32) ? (b0 >> c)
                                     : (c < 64) ? (b1 >> (c - 32))
                                                : (b2 >> (c - 64));
                        float tv = (bit & 1u) ? 1.0f : 0.0f;
                        float d = p - tv;
                        acc += d * d;
                    }
                }
            }
            // baseline: 0.5 * conf^2 over all 49 cells x 2 boxes
            for (int idx = lane; idx < 98; idx += 64) {
                int cell = idx >> 1;
                float p = preds[((size_t)b * CELLS + cell) * ROW + 4 + 5 * (idx & 1)];
                acc += 0.5f * p * p;
            }
        }
        __syncthreads();
    }

    // ---- reduction: wave shuffle, then block LDS, one atomic per block ----
    #pragma unroll
    for (int off = 32; off > 0; off >>= 1)
        acc += __shfl_down(acc, off, 64);
    if (lane == 0) s_red[w] = acc;
    __syncthreads();
    if (tid == 0) {
        float t = 0.0f;
        for (int i = 0; i < WAVES; ++i) t += s_red[i];
        atomicAdd(out, t);
    }
}

extern "C" void kernel_launch(void* const* d_in, const int* in_sizes, int n_in,
                              void* d_out, int out_size, void* d_ws, size_t ws_size,
                              hipStream_t stream) {
    const float* preds = (const float*)d_in[0];
    const float* gtb   = (const float*)d_in[1];
    const int*   gtl   = (const int*)d_in[2];
    float* out = (float*)d_out;

    zero_out_kernel<<<1, 1, 0, stream>>>(out);
    yolo_loss_kernel<<<GRID, BLOCK, 0, stream>>>(preds, gtb, gtl, out);
}

// Round 2
// 199.298 us; speedup vs baseline: 1.0351x; 1.0351x over previous
//
#include <hip/hip_runtime.h>
#include <cstdint>

#define BSZ   8192
#define NGT   8
#define ROW   90     // B*5 + C
#define CELLS 49     // 7*7
#define BLOCK 256
#define WPB   4      // waves per block
#define GRID  (BSZ / WPB)   // 2048 blocks -> 8192 waves, one batch item per wave

// Wave-per-batch, barrier-free main kernel. Phases A/B are computed
// redundantly by all 64 lanes (k = lane&7) so cross-lane exchange can use
// __shfl with a fully-active wave; redundant global loads hit the same L1
// lines so HBM traffic is unchanged. Partial sums go to d_ws (no atomics,
// no pre-zeroed output needed).
__launch_bounds__(BLOCK, 8)
__global__ void yolo_main(const float* __restrict__ preds,
                          const float* __restrict__ gtb,
                          const int*   __restrict__ gtl,
                          float* __restrict__ partial)
{
    const int tid  = threadIdx.x;
    const int lane = tid & 63;
    const int b    = blockIdx.x * WPB + (tid >> 6);   // 0..8191, one per wave
    const int k    = lane & 7;                        // GT index (x8 redundant)

    // ---- Phase A: per-GT computation (every lane, k = lane&7) ----
    const float4 gb = *(const float4*)(gtb + ((size_t)b * NGT + k) * 4);
    const float x1 = gb.x, y1 = gb.y, x2 = gb.z, y2 = gb.w;
    const float gcx = (x1 + x2) * 0.5f, gcy = (y1 + y2) * 0.5f;
    const float gw = x2 - x1, gh = y2 - y1;
    int gi = (int)(gcx * 7.0f); gi = gi < 0 ? 0 : (gi > 6 ? 6 : gi);
    int gj = (int)(gcy * 7.0f); gj = gj < 0 ? 0 : (gj > 6 ? 6 : gj);
    const int cell = gj * 7 + gi;

    const float* pc = preds + ((size_t)b * CELLS + cell) * ROW;  // 8B-aligned (ROW even)
    float p[10];
    #pragma unroll
    for (int i = 0; i < 5; ++i) {
        float2 q = *(const float2*)(pc + 2 * i);
        p[2*i] = q.x; p[2*i+1] = q.y;
    }

    float ious[2];
    #pragma unroll
    for (int bb = 0; bb < 2; ++bb) {
        float pcx = (p[bb*5+0] + (float)gi) / 7.0f;
        float pcy = (p[bb*5+1] + (float)gj) / 7.0f;
        float pw  = p[bb*5+2] * p[bb*5+2];
        float ph  = p[bb*5+3] * p[bb*5+3];
        float bx1 = pcx - pw * 0.5f, by1 = pcy - ph * 0.5f;
        float bx2 = pcx + pw * 0.5f, by2 = pcy + ph * 0.5f;
        float ix1 = fmaxf(bx1, x1), iy1 = fmaxf(by1, y1);
        float ix2 = fminf(bx2, x2), iy2 = fminf(by2, y2);
        float inter = fmaxf(ix2 - ix1, 0.0f) * fmaxf(iy2 - iy1, 0.0f);
        float a1 = fmaxf(bx2 - bx1, 0.0f) * fmaxf(by2 - by1, 0.0f);
        float a2 = fmaxf(x2 - x1, 0.0f) * fmaxf(y2 - y1, 0.0f);
        ious[bb] = inter / (a1 + a2 - inter + 1e-6f);
    }
    const int   best = (ious[1] > ious[0]) ? 1 : 0;   // first max wins
    const float iou  = ious[best];
    float cv[4] = { gcx * 7.0f - (float)gi, gcy * 7.0f - (float)gj,
                    sqrtf(gw), sqrtf(gh) };
    float pb[5];
    #pragma unroll
    for (int f = 0; f < 5; ++f) pb[f] = p[best*5 + f];
    const int label = gtl[(size_t)b * NGT + k];

    // ---- Phase B: scan semantics via shuffles (all lanes active) ----
    const int slot = cell * 2 + best;
    int cells[8], slots[8], labels[8];
    #pragma unroll
    for (int j = 0; j < 8; ++j) {
        cells[j]  = __shfl(cell,  j, 64);
        slots[j]  = __shfl(slot,  j, 64);
        labels[j] = __shfl(label, j, 64);
    }
    int fin = 1, rep = 1;
    uint32_t m0 = 0, m1 = 0, m2 = 0;
    #pragma unroll
    for (int j = 0; j < 8; ++j) {
        if (j > k && slots[j] == slot) fin = 0;      // later writer exists
        if (j < k && cells[j] == cell) rep = 0;      // earlier same cell
        if (cells[j] == cell) {                      // union of labels in cell
            int l = labels[j];
            if (l < 32)      m0 |= 1u << l;
            else if (l < 64) m1 |= 1u << (l - 32);
            else             m2 |= 1u << (l - 64);
        }
    }

    // ---- Phase C: accumulate ----
    float acc = 0.0f;

    // slot corrections (lanes 0..7 hold GT k's state directly)
    if (lane < 8 && fin) {
        float c = 0.0f;
        #pragma unroll
        for (int f = 0; f < 4; ++f) { float d = pb[f] - cv[f]; c += d * d; }
        acc += 5.0f * c;
        float d = pb[4] - iou;
        acc += d * d - 0.5f * pb[4] * pb[4];
    }

    // class corrections: group g (8 lanes) handles GT g's cell if rep_g
    {
        const int g = lane >> 3, sub = lane & 7;
        const int      rep_g = __shfl(rep, g, 64);
        const uint32_t g0 = __shfl(m0, g, 64);
        const uint32_t g1 = __shfl(m1, g, 64);
        const uint32_t g2 = __shfl(m2, g, 64);
        if (rep_g) {
            const float* pcl = preds + ((size_t)b * CELLS + cells[g]) * ROW + 10;
            #pragma unroll
            for (int t = 0; t < 10; ++t) {
                int c = sub + (t << 3);               // covers 0..79 once
                float pv = pcl[c];
                uint32_t bit = (c < 32) ? (g0 >> c)
                             : (c < 64) ? (g1 >> (c - 32))
                                        : (g2 >> (c - 64));
                float tv = (bit & 1u) ? 1.0f : 0.0f;
                float d = pv - tv;
                acc += d * d;
            }
        }
    }

    // noobj baseline: 0.5 * conf^2 over 49 cells x 2 boxes
    #pragma unroll
    for (int rr = 0; rr < 2; ++rr) {
        int idx = lane + 64 * rr;
        if (idx < 98) {
            int cc = idx >> 1;
            float pv = preds[((size_t)b * CELLS + cc) * ROW + 4 + 5 * (idx & 1)];
            acc += 0.5f * pv * pv;
        }
    }

    // ---- wave reduction, one plain store per wave ----
    #pragma unroll
    for (int off = 32; off > 0; off >>= 1)
        acc += __shfl_down(acc, off, 64);
    if (lane == 0) partial[b] = acc;
}

__global__ void yolo_reduce(const float* __restrict__ partial,
                            float* __restrict__ out)
{
    __shared__ float red[BLOCK / 64];
    const int tid = threadIdx.x, lane = tid & 63;
    float s = 0.0f;
    for (int i = tid; i < BSZ; i += BLOCK) s += partial[i];
    #pragma unroll
    for (int off = 32; off > 0; off >>= 1)
        s += __shfl_down(s, off, 64);
    if (lane == 0) red[tid >> 6] = s;
    __syncthreads();
    if (tid == 0) {
        float t = 0.0f;
        #pragma unroll
        for (int i = 0; i < BLOCK / 64; ++i) t += red[i];
        out[0] = t;
    }
}

extern "C" void kernel_launch(void* const* d_in, const int* in_sizes, int n_in,
                              void* d_out, int out_size, void* d_ws, size_t ws_size,
                              hipStream_t stream) {
    const float* preds = (const float*)d_in[0];
    const float* gtb   = (const float*)d_in[1];
    const int*   gtl   = (const int*)d_in[2];
    float* partial = (float*)d_ws;     // 8192 floats, overwritten every call
    float* out     = (float*)d_out;

    yolo_main<<<GRID, BLOCK, 0, stream>>>(preds, gtb, gtl, partial);
    yolo_reduce<<<1, BLOCK, 0, stream>>>(partial, out);
}

// Round 3
// 193.937 us; speedup vs baseline: 1.0637x; 1.0276x over previous
//
#include <hip/hip_runtime.h>
#include <cstdint>

#define BSZ   8192
#define NGT   8
#define ROW   90     // B*5 + C
#define CELLS 49     // 7*7
#define BLOCK 256
#define WPB   4      // waves per block
#define GRID  (BSZ / WPB)   // 2048 blocks, one batch item per wave

// Wave-per-batch, barrier-free-in-loop main kernel. All 64 lanes compute
// phases A/B redundantly (k = lane&7) so cross-lane exchange is pure __shfl.
// Memory schedule: independent conf-baseline loads issued first; class-row
// loads issued as soon as `cell` geometry is known (they do NOT depend on
// the pred-cell loads), so the two gather rounds overlap. 2 dependent
// memory rounds total instead of 3.
__launch_bounds__(BLOCK, 8)
__global__ void yolo_main(const float* __restrict__ preds,
                          const float* __restrict__ gtb,
                          const int*   __restrict__ gtl,
                          float* __restrict__ partial)
{
    __shared__ float s_red[WPB];
    const int tid  = threadIdx.x;
    const int lane = tid & 63;
    const int w    = tid >> 6;
    const int b    = blockIdx.x * WPB + w;   // 0..8191
    const int k    = lane & 7;               // GT index (x8 redundant)

    const float* pb_base = preds + (size_t)b * CELLS * ROW;

    // ---- issue independent loads first: conf baseline, gt box, gt label ----
    // conf indices: idx in [0,98): cell = idx>>1, channel 4 or 9
    const float conf0 = pb_base[(size_t)(lane >> 1) * ROW + 4 + 5 * (lane & 1)];
    float conf1 = 0.0f;
    const int idx1 = lane + 64;
    if (idx1 < 98)
        conf1 = pb_base[(size_t)(idx1 >> 1) * ROW + 4 + 5 * (idx1 & 1)];

    const float4 gb = *(const float4*)(gtb + ((size_t)b * NGT + k) * 4);
    const int label = gtl[(size_t)b * NGT + k];

    // ---- geometry (depends only on gtb) ----
    const float x1 = gb.x, y1 = gb.y, x2 = gb.z, y2 = gb.w;
    const float gcx = (x1 + x2) * 0.5f, gcy = (y1 + y2) * 0.5f;
    const float gw = x2 - x1, gh = y2 - y1;
    int gi = (int)(gcx * 7.0f); gi = gi < 0 ? 0 : (gi > 6 ? 6 : gi);
    int gj = (int)(gcy * 7.0f); gj = gj < 0 ? 0 : (gj > 6 ? 6 : gj);
    const int cell = gj * 7 + gi;

    // ---- issue pred-cell loads (own k's cell) ----
    const float* pc = pb_base + (size_t)cell * ROW;   // 8B aligned (ROW even)
    float p[10];
    #pragma unroll
    for (int i = 0; i < 5; ++i) {
        float2 q = *(const float2*)(pc + 2 * i);
        p[2*i] = q.x; p[2*i+1] = q.y;
    }

    // ---- broadcast cells; issue class-row loads (parallel with pc loads) ----
    int cells[8], labels[8];
    #pragma unroll
    for (int j = 0; j < 8; ++j) {
        cells[j]  = __shfl(cell,  j, 64);
        labels[j] = __shfl(label, j, 64);
    }
    const int g = lane >> 3, sub = lane & 7;
    const float* pcl = pb_base + (size_t)cells[g] * ROW + 10;
    float clsv[10];
    #pragma unroll
    for (int t = 0; t < 10; ++t) clsv[t] = pcl[sub + (t << 3)];  // 0..79 once

    // ---- iou / best / targets (consumes pc) ----
    float ious[2];
    #pragma unroll
    for (int bb = 0; bb < 2; ++bb) {
        float pcx = (p[bb*5+0] + (float)gi) / 7.0f;
        float pcy = (p[bb*5+1] + (float)gj) / 7.0f;
        float pw  = p[bb*5+2] * p[bb*5+2];
        float ph  = p[bb*5+3] * p[bb*5+3];
        float bx1 = pcx - pw * 0.5f, by1 = pcy - ph * 0.5f;
        float bx2 = pcx + pw * 0.5f, by2 = pcy + ph * 0.5f;
        float ix1 = fmaxf(bx1, x1), iy1 = fmaxf(by1, y1);
        float ix2 = fminf(bx2, x2), iy2 = fminf(by2, y2);
        float inter = fmaxf(ix2 - ix1, 0.0f) * fmaxf(iy2 - iy1, 0.0f);
        float a1 = fmaxf(bx2 - bx1, 0.0f) * fmaxf(by2 - by1, 0.0f);
        float a2 = fmaxf(x2 - x1, 0.0f) * fmaxf(y2 - y1, 0.0f);
        ious[bb] = inter / (a1 + a2 - inter + 1e-6f);
    }
    const int   best = (ious[1] > ious[0]) ? 1 : 0;   // first max wins
    const float iou  = ious[best];
    float cv[4] = { gcx * 7.0f - (float)gi, gcy * 7.0f - (float)gj,
                    sqrtf(gw), sqrtf(gh) };
    float pbx[5];
    #pragma unroll
    for (int f = 0; f < 5; ++f) pbx[f] = p[best*5 + f];

    // ---- scan semantics: last writer per slot, first occurrence per cell ----
    const int slot = cell * 2 + best;
    int slots[8];
    #pragma unroll
    for (int j = 0; j < 8; ++j) slots[j] = __shfl(slot, j, 64);
    int fin = 1, rep = 1;
    uint32_t m0 = 0, m1 = 0, m2 = 0;
    #pragma unroll
    for (int j = 0; j < 8; ++j) {
        if (j > k && slots[j] == slot) fin = 0;
        if (j < k && cells[j] == cell) rep = 0;
        if (cells[j] == cell) {
            int l = labels[j];
            if (l < 32)      m0 |= 1u << l;
            else if (l < 64) m1 |= 1u << (l - 32);
            else             m2 |= 1u << (l - 64);
        }
    }

    // ---- accumulate ----
    float acc = 0.5f * conf0 * conf0 + 0.5f * conf1 * conf1;

    if (lane < 8 && fin) {   // slot corrections (lane k holds GT k directly)
        float c = 0.0f;
        #pragma unroll
        for (int f = 0; f < 4; ++f) { float d = pbx[f] - cv[f]; c += d * d; }
        acc += 5.0f * c;
        float d = pbx[4] - iou;
        acc += d * d - 0.5f * pbx[4] * pbx[4];
    }

    {   // class corrections for group g's cell, gated on rep_g
        const int      rep_g = __shfl(rep, g, 64);
        const uint32_t g0 = __shfl(m0, g, 64);
        const uint32_t g1 = __shfl(m1, g, 64);
        const uint32_t g2 = __shfl(m2, g, 64);
        if (rep_g) {
            #pragma unroll
            for (int t = 0; t < 10; ++t) {
                int c = sub + (t << 3);
                uint32_t bit = (c < 32) ? (g0 >> c)
                             : (c < 64) ? (g1 >> (c - 32))
                                        : (g2 >> (c - 64));
                float tv = (bit & 1u) ? 1.0f : 0.0f;
                float d = clsv[t] - tv;
                acc += d * d;
            }
        }
    }

    // ---- wave reduce, block combine via LDS, one store per block ----
    #pragma unroll
    for (int off = 32; off > 0; off >>= 1)
        acc += __shfl_down(acc, off, 64);
    if (lane == 0) s_red[w] = acc;
    __syncthreads();
    if (tid == 0) {
        float t = 0.0f;
        #pragma unroll
        for (int i = 0; i < WPB; ++i) t += s_red[i];
        partial[blockIdx.x] = t;
    }
}

__global__ void yolo_reduce(const float* __restrict__ partial,
                            float* __restrict__ out)
{
    __shared__ float red[BLOCK / 64];
    const int tid = threadIdx.x, lane = tid & 63;
    float s = 0.0f;
    #pragma unroll
    for (int i = 0; i < GRID / BLOCK; ++i)   // 2048 / 256 = 8
        s += partial[tid + i * BLOCK];
    #pragma unroll
    for (int off = 32; off > 0; off >>= 1)
        s += __shfl_down(s, off, 64);
    if (lane == 0) red[tid >> 6] = s;
    __syncthreads();
    if (tid == 0) {
        float t = 0.0f;
        #pragma unroll
        for (int i = 0; i < BLOCK / 64; ++i) t += red[i];
        out[0] = t;
    }
}

extern "C" void kernel_launch(void* const* d_in, const int* in_sizes, int n_in,
                              void* d_out, int out_size, void* d_ws, size_t ws_size,
                              hipStream_t stream) {
    const float* preds = (const float*)d_in[0];
    const float* gtb   = (const float*)d_in[1];
    const int*   gtl   = (const int*)d_in[2];
    float* partial = (float*)d_ws;     // 2048 floats, fully overwritten each call
    float* out     = (float*)d_out;

    yolo_main<<<GRID, BLOCK, 0, stream>>>(preds, gtb, gtl, partial);
    yolo_reduce<<<1, BLOCK, 0, stream>>>(partial, out);
}